// Round 9
// baseline (223.285 us; speedup 1.0000x reference)
//
#include <hip/hip_runtime.h>
#include <stdint.h>

#define BATCH 8
#define SEQ   2048
#define DIM   512

typedef __attribute__((ext_vector_type(8)))  short short8;    // 8 bf16 (4 VGPRs)
typedef __attribute__((ext_vector_type(16))) float floatx16;  // 32x32 C/D frag

static __device__ __forceinline__ unsigned short f32_bf16(float f) {
  unsigned u = __builtin_bit_cast(unsigned, f);
  u += 0x7FFFu + ((u >> 16) & 1u);          // round-to-nearest-even
  return (unsigned short)(u >> 16);
}
static __device__ __forceinline__ short8 ld_frag8(const unsigned short* p) {
  return __builtin_bit_cast(short8, *reinterpret_cast<const uint4*>(p));
}
static __device__ __forceinline__ void gld_lds16(const unsigned short* g, unsigned short* l) {
  __builtin_amdgcn_global_load_lds((const __attribute__((address_space(1))) unsigned int*)g,
                                   (__attribute__((address_space(3))) unsigned int*)l, 16, 0, 0);
}
static __device__ __forceinline__ float bfu(unsigned short u) {
  return __builtin_bit_cast(float, (unsigned)u << 16);
}
static __device__ __forceinline__ int key8(int r) { return (r ^ (r >> 3)) & 7; }

static __device__ __forceinline__ void wait_vm2_barrier() {
  asm volatile("s_waitcnt vmcnt(2)" ::: "memory");   // prev stage landed; next (2 loads) in flight
  __builtin_amdgcn_s_barrier();
  __builtin_amdgcn_sched_barrier(0);
}
static __device__ __forceinline__ void wait_vm0_barrier() {
  asm volatile("s_waitcnt vmcnt(0)" ::: "memory");
  __builtin_amdgcn_s_barrier();
  __builtin_amdgcn_sched_barrier(0);
}
static __device__ __forceinline__ void wait_vm2_lgkm_barrier() {
  asm volatile("s_waitcnt vmcnt(2) lgkmcnt(0)" ::: "memory");  // + sP ds_writes visible
  __builtin_amdgcn_s_barrier();
  __builtin_amdgcn_sched_barrier(0);
}

// ---------------- prep: x -> xn (bf16 x-hat, row-major) and xt (bf16 x^T, BLOCKED) ---------
// xt layout: [b][jt][d][j&31]  (jt = j>>5) -> each block owns ONE contiguous 32KB chunk.
// grid 512 = 8 batches (XCD-pinned &7) x 64 j-tiles of 32 rows ; 256 threads
__global__ __launch_bounds__(256) void prep_kernel(const float* __restrict__ x,
                                                   unsigned short* __restrict__ xn,
                                                   unsigned short* __restrict__ xt) {
  const int b   = blockIdx.x & 7;
  const int jt  = blockIdx.x >> 3;     // 0..63
  const int t   = threadIdx.x;
  const int row = t >> 3;              // 0..31
  const int oct = t & 7;               // 0..7

  __shared__ unsigned short xs[512 * 34];   // [d][j] bf16, pitch 34 u16 (34.8 KB)

  const long rowg = ((long)b * SEQ + jt * 32 + row) * DIM;
  const float* xp = x + rowg;

  float4 v[16];
#pragma unroll
  for (int k = 0; k < 16; ++k)
    v[k] = *reinterpret_cast<const float4*>(xp + k * 32 + oct * 4);

  float acc = 0.f;
#pragma unroll
  for (int k = 0; k < 16; ++k)
    acc += v[k].x*v[k].x + v[k].y*v[k].y + v[k].z*v[k].z + v[k].w*v[k].w;
  acc += __shfl_xor(acc, 1);
  acc += __shfl_xor(acc, 2);
  acc += __shfl_xor(acc, 4);
  const float sc = 1.f / (sqrtf(acc) + 1e-12f);

  // xn straight from registers
  unsigned short* xnp = xn + rowg + oct * 4;
#pragma unroll
  for (int k = 0; k < 16; ++k) {
    ushort4 pk;
    pk.x = f32_bf16(v[k].x * sc); pk.y = f32_bf16(v[k].y * sc);
    pk.z = f32_bf16(v[k].z * sc); pk.w = f32_bf16(v[k].w * sc);
    *reinterpret_cast<ushort4*>(xnp + k * 32) = pk;
  }

  // LDS transpose staging: scalar u16 writes, bank = 4*oct + row/2 + const -> free
#pragma unroll
  for (int k = 0; k < 16; ++k) {
    const int d = k * 32 + oct * 4;
    xs[(d + 0) * 34 + row] = f32_bf16(v[k].x);
    xs[(d + 1) * 34 + row] = f32_bf16(v[k].y);
    xs[(d + 2) * 34 + row] = f32_bf16(v[k].z);
    xs[(d + 3) * 34 + row] = f32_bf16(v[k].w);
  }
  __syncthreads();

  // xt chunk store: contiguous 32KB, fully coalesced.
  unsigned short* xtb = xt + (size_t)(b * 64 + jt) * (512 * 32);
#pragma unroll
  for (int it = 0; it < 8; ++it) {
    const int a = t >> 2;                      // 0..63 d-sub
    const int q = (t & 3) ^ ((t >> 4) & 3);    // read/store group 0..3
    const int d = it * 64 + a;
    const unsigned* bp = reinterpret_cast<const unsigned*>(&xs[d * 34 + q * 8]);
    uint4 o;
    o.x = bp[0]; o.y = bp[1]; o.z = bp[2]; o.w = bp[3];
    *reinterpret_cast<uint4*>(xtb + d * 32 + q * 8) = o;
  }
}

// ---------------- fused flash kernel: S -> P=exp(S^2-1) -> O += P.x, l += rowsum(P) --------
// grid 256 = 8 batches (XCD-pinned) x 32 i-tiles of 64 rows ; 512 threads = 8 waves.
// Wave (wi=w&1, wq=w>>1): S sub-tile [32 i x 32 j], PV sub-tile [32 i x 128 d].
// LDS (~130 KB, 1 blk/CU): sQ 64KB resident swizzled Q-panel; sS 48KB = 3 x 16KB stage
// slots (S: [128 j x 64 k] chunks; PV: [512 d x 16 j] chunks — same slots, phase-aliased);
// sP 17.4KB bf16 P (pitch 136 = bank-clean). Both stage-trains: depth-2 counted vmcnt(2),
// slot p%3 (r6-traced schedule). A-operands never restage (sQ/sP). No atomics, no lw.
__global__ __launch_bounds__(512, 2) void fused_kernel(const unsigned short* __restrict__ xn,
                                                       const unsigned short* __restrict__ xt,
                                                       float* __restrict__ out) {
  const int b  = blockIdx.x & 7;
  const int i0 = (blockIdx.x >> 3) * 64;
  const int tid  = threadIdx.x;
  const int lane = tid & 63;
  const int ln   = lane & 31;
  const int half = lane >> 5;
  const int w    = tid >> 6;         // 0..7
  const int wi   = w & 1;            // i-half
  const int wq   = w >> 1;           // j-strip (S) / d-strip (PV), 0..3

  __shared__ __align__(16) unsigned short sQ[64 * 512];   // 64 KB
  __shared__ __align__(16) unsigned short sS[3 * 8192];   // 48 KB, 3 slots
  __shared__ __align__(16) unsigned short sP[64 * 136];   // 17.4 KB
  __shared__ float sL2[4 * 64];
  __shared__ float sLi[64];

  const unsigned short* xb  = xn + (size_t)b * SEQ * DIM;
  const unsigned short* xtb = xt + (size_t)b * DIM * SEQ;   // blocked chunks

  if (tid < 256) sL2[tid] = 0.f;

  // ---- stage resident sQ: [64 rows][512 k], low-3-bit granule swizzle g^key(row) ----
#pragma unroll
  for (int k = 0; k < 8; ++k) {
    const int u = tid + k * 512;
    const int row = u >> 6, g = u & 63;          // row wave-uniform per k
    const int gs = (g & 56) | ((g & 7) ^ key8(row));
    gld_lds16(xb + (size_t)(i0 + row) * DIM + gs * 8, sQ + u * 8);
  }

  floatx16 acc_o[4];
#pragma unroll
  for (int nt = 0; nt < 4; ++nt)
#pragma unroll
    for (int e = 0; e < 16; ++e) acc_o[nt][e] = 0.f;

  const int ri   = wi * 32 + ln;      // A-row for S and PV
  const int keyi = key8(ri);
  const int rj   = wq * 32 + ln;      // S B-row
  const int keyj = key8(rj);

  wait_vm0_barrier();                 // sQ staged, sL2 zeroed

  for (int jt = 0; jt < 16; ++jt) {
    const int j0 = jt * 128;

    // ---------------- S train: 8 phases of [128 j x 64 k] ----------------
    auto stage_s = [&](int p, int s) {
      unsigned short* dst = sS + s * 8192;
#pragma unroll
      for (int k = 0; k < 2; ++k) {
        const int u = tid + k * 512;
        const int row = u >> 3, c = u & 7;
        gld_lds16(xb + (size_t)(j0 + row) * DIM + p * 64 + ((c ^ key8(row)) * 8), dst + u * 8);
      }
    };
    stage_s(0, 0); stage_s(1, 1);
    wait_vm2_barrier();

    floatx16 acc_s;
#pragma unroll
    for (int e = 0; e < 16; ++e) acc_s[e] = 0.f;

    for (int p = 0; p < 8; ++p) {
      if (p + 2 < 8) { stage_s(p + 2, (p + 2) % 3); __builtin_amdgcn_sched_barrier(0); }
      const unsigned short* cB = sS + (p % 3) * 8192;
#pragma unroll
      for (int kk = 0; kk < 4; ++kk) {
        const int gq = p * 8 + kk * 2 + half;
        const short8 aq = ld_frag8(sQ + ri * 512 + ((gq & 56) | ((gq & 7) ^ keyi)) * 8);
        const short8 bq = ld_frag8(cB + rj * 64 + (((kk * 2 + half) ^ keyj) * 8));
        acc_s = __builtin_amdgcn_mfma_f32_32x32x16_bf16(aq, bq, acc_s, 0, 0, 0);
      }
      if (p + 2 < 8) wait_vm2_barrier();
      else           wait_vm0_barrier();
    }

    // ---- P epilogue: bf16 once; same bits feed sP, PV, and the row-sum ----
    unsigned short us[16];
#pragma unroll
    for (int r = 0; r < 16; ++r) {
      const float s = acc_s[r];
      us[r] = f32_bf16(__expf(__builtin_fmaf(s, s, -1.0f)));
    }
#pragma unroll
    for (int r = 0; r < 16; ++r) {
      float v = bfu(us[r]);
      v += __shfl_xor(v, 1);
      v += __shfl_xor(v, 2);
      v += __shfl_xor(v, 4);
      v += __shfl_xor(v, 8);
      v += __shfl_xor(v, 16);
      if (ln == 0) {
        const int row = wi * 32 + (r & 3) + 8 * (r >> 2) + 4 * half;
        sL2[wq * 64 + row] += v;    // slot private to (wq,row): no race
      }
    }
#pragma unroll
    for (int r = 0; r < 16; ++r) {
      const int row = wi * 32 + (r & 3) + 8 * (r >> 2) + 4 * half;
      sP[row * 136 + wq * 32 + ln] = us[r];
    }

    // ---------------- PV train: 8 phases of [512 d x 16 j] ----------------
    auto stage_pv = [&](int q, int s) {
      unsigned short* dst = sS + s * 8192;
      const unsigned short* ch = xtb + (size_t)(jt * 4 + (q >> 1)) * 16384 + (q & 1) * 16;
#pragma unroll
      for (int k = 0; k < 2; ++k) {
        const int u = tid + k * 512;
        const int d = u >> 1, g = u & 1;
        gld_lds16(ch + d * 32 + ((g ^ (d & 1)) * 8), dst + u * 8);
      }
    };
    stage_pv(0, 0); stage_pv(1, 1);
    wait_vm2_lgkm_barrier();          // pv0 landed ; sP writes drained & visible

    for (int q = 0; q < 8; ++q) {
      if (q + 2 < 8) { stage_pv(q + 2, (q + 2) % 3); __builtin_amdgcn_sched_barrier(0); }
      const unsigned short* cV = sS + (q % 3) * 8192;
      const short8 ap = ld_frag8(sP + ri * 136 + q * 16 + half * 8);
#pragma unroll
      for (int nt = 0; nt < 4; ++nt) {
        const int d = wq * 128 + nt * 32 + ln;
        const short8 bv = ld_frag8(cV + d * 16 + ((half ^ (d & 1)) * 8));
        acc_o[nt] = __builtin_amdgcn_mfma_f32_32x32x16_bf16(ap, bv, acc_o[nt], 0, 0, 0);
      }
      if (q + 2 < 8) wait_vm2_barrier();
      else           wait_vm0_barrier();
    }
  }

  // ---- finalize l (all sL2 writes precede the last PV-prologue barrier) ----
  if (tid < 64) {
    const float l = sL2[tid] + sL2[64 + tid] + sL2[128 + tid] + sL2[192 + tid];
    sLi[tid] = 1.0f / l;
  }
  __syncthreads();

  // ---- epilogue: O / l, coalesced fp32 stores (32 consecutive floats per half-wave) ----
#pragma unroll
  for (int r = 0; r < 16; ++r) {
    const int row = wi * 32 + (r & 3) + 8 * (r >> 2) + 4 * half;
    const float inv = sLi[row];
#pragma unroll
    for (int nt = 0; nt < 4; ++nt)
      out[((size_t)b * SEQ + i0 + row) * DIM + wq * 128 + nt * 32 + ln] = acc_o[nt][r] * inv;
  }
}

extern "C" void kernel_launch(void* const* d_in, const int* in_sizes, int n_in,
                              void* d_out, int out_size, void* d_ws, size_t ws_size,
                              hipStream_t stream) {
  const float* x = (const float*)d_in[0];
  float* outp = (float*)d_out;

  unsigned short* xn = (unsigned short*)d_ws;                        // 16.78 MB
  unsigned short* xt = xn + (size_t)BATCH * SEQ * DIM;               // 16.78 MB (blocked)

  prep_kernel <<<BATCH * (SEQ / 32), 256, 0, stream>>>(x, xn, xt);
  fused_kernel<<<BATCH * (SEQ / 64), 512, 0, stream>>>(xn, xt, outp);
}

// Round 10
// 166.231 us; speedup vs baseline: 1.3432x; 1.3432x over previous
//
#include <hip/hip_runtime.h>
#include <stdint.h>

#define BATCH 8
#define SEQ   2048
#define DIM   512

typedef __attribute__((ext_vector_type(8)))  short short8;    // 8 bf16 (4 VGPRs)
typedef __attribute__((ext_vector_type(16))) float floatx16;  // 32x32 C/D frag

static __device__ __forceinline__ unsigned short f32_bf16(float f) {
  unsigned u = __builtin_bit_cast(unsigned, f);
  u += 0x7FFFu + ((u >> 16) & 1u);          // round-to-nearest-even
  return (unsigned short)(u >> 16);
}
static __device__ __forceinline__ short8 ld_frag8(const unsigned short* p) {
  return __builtin_bit_cast(short8, *reinterpret_cast<const uint4*>(p));
}
static __device__ __forceinline__ void gld_lds16(const unsigned short* g, unsigned short* l) {
  __builtin_amdgcn_global_load_lds((const __attribute__((address_space(1))) unsigned int*)g,
                                   (__attribute__((address_space(3))) unsigned int*)l, 16, 0, 0);
}
static __device__ __forceinline__ float bf_lo(unsigned u) {
  return __builtin_bit_cast(float, u << 16);
}
static __device__ __forceinline__ float bf_hi(unsigned u) {
  return __builtin_bit_cast(float, u & 0xFFFF0000u);
}
static __device__ __forceinline__ float bfu(unsigned short u) {
  return __builtin_bit_cast(float, (unsigned)u << 16);
}
static __device__ __forceinline__ void wait_vm0_barrier() {
  asm volatile("s_waitcnt vmcnt(0)" ::: "memory");
  __builtin_amdgcn_s_barrier();
  __builtin_amdgcn_sched_barrier(0);
}

// ---------------- prep v2: x -> xn (bf16 x-hat) and xt (bf16 x^T, BLOCKED 16-wide) --------
// r9 diagnosis: prep ~55us at 2 blk/CU (serial load->norm->transpose->store chain, memory
// pipe idle during compute). Fix: 16-row j-tiles -> grid 1024 = 4 blk/CU (2x TLP),
// LDS 18.4KB pitch-18. xn stores now full 128B lines/row/instr. xt chunk [512 d][16 j].
// grid 1024 = 8 batches (XCD-pinned &7) x 128 j-tiles of 16 rows ; 256 threads
__global__ __launch_bounds__(256) void prep_kernel(const float* __restrict__ x,
                                                   unsigned short* __restrict__ xn,
                                                   unsigned short* __restrict__ xt) {
  const int b   = blockIdx.x & 7;
  const int jt  = blockIdx.x >> 3;     // 0..127
  const int t   = threadIdx.x;
  const int row = t >> 4;              // 0..15
  const int seg = t & 15;              // 0..15

  __shared__ unsigned short xs[512 * 18];   // [d][j] bf16, pitch 18 u16 (18.4 KB)

  const long rowg = ((long)b * SEQ + jt * 16 + row) * DIM;
  const float* xp = x + rowg;

  float4 v[8];
#pragma unroll
  for (int k = 0; k < 8; ++k)
    v[k] = *reinterpret_cast<const float4*>(xp + k * 64 + seg * 4);

  float acc = 0.f;
#pragma unroll
  for (int k = 0; k < 8; ++k)
    acc += v[k].x*v[k].x + v[k].y*v[k].y + v[k].z*v[k].z + v[k].w*v[k].w;
  acc += __shfl_xor(acc, 1);
  acc += __shfl_xor(acc, 2);
  acc += __shfl_xor(acc, 4);
  acc += __shfl_xor(acc, 8);
  const float sc = 1.f / (sqrtf(acc) + 1e-12f);

  // xn straight from registers: per instr, 4 rows x 128B full lines
  unsigned short* xnp = xn + rowg + seg * 4;
#pragma unroll
  for (int k = 0; k < 8; ++k) {
    ushort4 pk;
    pk.x = f32_bf16(v[k].x * sc); pk.y = f32_bf16(v[k].y * sc);
    pk.z = f32_bf16(v[k].z * sc); pk.w = f32_bf16(v[k].w * sc);
    *reinterpret_cast<ushort4*>(xnp + k * 64) = pk;
  }

  // LDS transpose staging (scalar u16 writes, <=4-way aliasing)
#pragma unroll
  for (int k = 0; k < 8; ++k) {
    const int d = k * 64 + seg * 4;
    xs[(d + 0) * 18 + row] = f32_bf16(v[k].x);
    xs[(d + 1) * 18 + row] = f32_bf16(v[k].y);
    xs[(d + 2) * 18 + row] = f32_bf16(v[k].z);
    xs[(d + 3) * 18 + row] = f32_bf16(v[k].w);
  }
  __syncthreads();

  // xt chunk store: [512 d][16 j] = 16KB contiguous; wave instr = contiguous 1KB.
  // LDS gather: u32 reads at 9d+4q+c per lane -> 2-way bank aliasing (free).
  unsigned short* xtb = xt + (size_t)(b * 128 + jt) * (512 * 16);
#pragma unroll
  for (int it = 0; it < 4; ++it) {
    const int d = it * 128 + (t >> 1);
    const int q = t & 1;
    const unsigned* bp = reinterpret_cast<const unsigned*>(&xs[d * 18 + q * 8]);
    uint4 o;
    o.x = bp[0]; o.y = bp[1]; o.z = bp[2]; o.w = bp[3];
    *reinterpret_cast<uint4*>(xtb + d * 16 + q * 8) = o;
  }
}

// ---------------- gemm1 (symmetric, 2-phase prefetch, BK=64 — r5 proven): ----------------
// P[b,i,j] = bf16(exp(S^2-1)), upper-triangle tiles (grid 8 x 136).
// STAGE(kc+1) issued BEFORE compute(kc); raw s_barrier + asm vmcnt(0) once per kc.
// LDS 64KB dbuf (2 blk/CU). Mirror tile routed through LDS -> full-line stores.
__global__ __launch_bounds__(256, 2) void gemm1_kernel(const unsigned short* __restrict__ xn,
                                                       unsigned short* __restrict__ P,
                                                       float* __restrict__ lw) {
  const int b   = blockIdx.x & 7;
  int idx = blockIdx.x >> 3;           // 0..135 -> (ti, tj), ti <= tj
  int ti = 0;
#pragma unroll 1
  while (idx >= 16 - ti) { idx -= 16 - ti; ++ti; }
  const int tj = ti + idx;
  const int i0 = ti * 128;
  const int j0 = tj * 128;
  const bool diag = (ti == tj);

  const int tid  = threadIdx.x;
  const int w    = tid >> 6;
  const int lane = tid & 63;
  const int ln   = lane & 31;
  const int half = lane >> 5;

  // dbuf: buf k at k*16384 (A 8192 u16, B 8192 u16). sP (17408 u16) aliases buf0.
  __shared__ __align__(16) unsigned short smem[32768];   // 64 KB

  const unsigned short* xb = xn + (long)b * SEQ * DIM;
  const unsigned short* Ag = xb + (long)i0 * DIM;
  const unsigned short* Bg = xb + (long)j0 * DIM;

  floatx16 acc[2][2];
#pragma unroll
  for (int mt = 0; mt < 2; ++mt)
#pragma unroll
    for (int nt = 0; nt < 2; ++nt)
#pragma unroll
      for (int i = 0; i < 16; ++i) acc[mt][nt][i] = 0.f;

  const int r0 = (w >> 1) * 64;
  const int c0 = (w & 1) * 64;

  // ---- prologue: stage kc=0 into buf0 ----
  {
    unsigned short* bA = smem;
    unsigned short* bB = smem + 8192;
#pragma unroll
    for (int k = 0; k < 4; ++k) {
      int u = tid + k * 256;
      int row = u >> 3, c = u & 7;
      int gc = (c ^ ((row ^ (row >> 3)) & 7)) * 8;
      gld_lds16(Ag + (long)row * DIM + gc, bA + u * 8);
      if (!diag) gld_lds16(Bg + (long)row * DIM + gc, bB + u * 8);
    }
  }
  wait_vm0_barrier();

  for (int kc = 0; kc < 8; ++kc) {
    const int cur = kc & 1;
    if (kc < 7) {            // prefetch next chunk into the other buffer
      unsigned short* bA = smem + (cur ^ 1) * 16384;
      unsigned short* bB = bA + 8192;
      const int ko = (kc + 1) * 64;
#pragma unroll
      for (int k = 0; k < 4; ++k) {
        int u = tid + k * 256;
        int row = u >> 3, c = u & 7;
        int gc = (c ^ ((row ^ (row >> 3)) & 7)) * 8;
        gld_lds16(Ag + (long)row * DIM + ko + gc, bA + u * 8);
        if (!diag) gld_lds16(Bg + (long)row * DIM + ko + gc, bB + u * 8);
      }
      __builtin_amdgcn_sched_barrier(0);   // keep the issue cluster ahead of compute
    }
    unsigned short* cA = smem + cur * 16384;
    unsigned short* cB = diag ? cA : cA + 8192;
#pragma unroll
    for (int kk = 0; kk < 4; ++kk) {
      const int cc = kk * 2 + half;
      short8 af[2], bfr[2];
#pragma unroll
      for (int mt = 0; mt < 2; ++mt) {
        int r = r0 + mt * 32 + ln;
        af[mt] = ld_frag8(cA + r * 64 + ((cc ^ ((r ^ (r >> 3)) & 7)) * 8));
      }
#pragma unroll
      for (int nt = 0; nt < 2; ++nt) {
        int r = c0 + nt * 32 + ln;
        bfr[nt] = ld_frag8(cB + r * 64 + ((cc ^ ((r ^ (r >> 3)) & 7)) * 8));
      }
#pragma unroll
      for (int mt = 0; mt < 2; ++mt)
#pragma unroll
        for (int nt = 0; nt < 2; ++nt)
          acc[mt][nt] = __builtin_amdgcn_mfma_f32_32x32x16_bf16(af[mt], bfr[nt], acc[mt][nt], 0, 0, 0);
    }
    wait_vm0_barrier();      // prefetch landed during compute; buffers safe to swap
  }

  // epilogue: p = bf16(exp(s^2-1)) once into registers; feed sP, mirror, sums
  unsigned short pb[2][2][16];
  unsigned short* sP = smem;
#pragma unroll
  for (int mt = 0; mt < 2; ++mt)
#pragma unroll
    for (int nt = 0; nt < 2; ++nt) {
      const int col = c0 + nt * 32 + ln;
#pragma unroll
      for (int r = 0; r < 16; ++r) {
        float s = acc[mt][nt][r];
        unsigned short pv = f32_bf16(__expf(__builtin_fmaf(s, s, -1.0f)));
        pb[mt][nt][r] = pv;
        int row = r0 + mt * 32 + (r & 3) + 8 * (r >> 2) + 4 * half;
        sP[row * 136 + col] = pv;
      }
    }
  __syncthreads();

  unsigned short* Pg = P + (long)b * SEQ * SEQ;
  float* lwi = lw + b * SEQ + i0;
  float* lwj = lw + b * SEQ + j0;

  // tile (ti,tj): coalesced stores + fused row-sums
#pragma unroll
  for (int k = 0; k < 8; ++k) {
    int u = tid + k * 256;
    int row = u >> 4, c16 = u & 15;
    uint4 o = *reinterpret_cast<const uint4*>(sP + row * 136 + c16 * 8);
    *reinterpret_cast<uint4*>(Pg + (long)(i0 + row) * SEQ + j0 + c16 * 8) = o;
    float s = bf_lo(o.x) + bf_hi(o.x) + bf_lo(o.y) + bf_hi(o.y)
            + bf_lo(o.z) + bf_hi(o.z) + bf_lo(o.w) + bf_hi(o.w);
    s += __shfl_xor(s, 1);
    s += __shfl_xor(s, 2);
    s += __shfl_xor(s, 4);
    s += __shfl_xor(s, 8);
    if ((tid & 15) == 0) atomicAdd(&lwi[row], s);
  }

  if (!diag) {
    // column sums (= row sums of the mirror tile) from the exact bf16 register values
#pragma unroll
    for (int nt = 0; nt < 2; ++nt) {
      const int c = c0 + nt * 32 + ln;
      float s = 0.f;
#pragma unroll
      for (int mt = 0; mt < 2; ++mt)
#pragma unroll
        for (int r = 0; r < 16; ++r) s += bfu(pb[mt][nt][r]);
      s += __shfl_xor(s, 32);           // combine the two row-halves of this wave
      if (half == 0) atomicAdd(&lwj[c], s);
    }
    __syncthreads();                    // direct-tile reads of sP complete
    // rewrite sP TRANSPOSED (sP[c][i]) from registers, then store coalesced full lines
#pragma unroll
    for (int nt = 0; nt < 2; ++nt) {
      const int c = c0 + nt * 32 + ln;
#pragma unroll
      for (int mt = 0; mt < 2; ++mt)
#pragma unroll
        for (int r = 0; r < 16; ++r) {
          const int row = r0 + mt * 32 + (r & 3) + 8 * (r >> 2) + 4 * half;
          sP[c * 136 + row] = pb[mt][nt][r];
        }
    }
    __syncthreads();
#pragma unroll
    for (int k = 0; k < 8; ++k) {
      int u = tid + k * 256;
      int row = u >> 4, c16 = u & 15;   // row = mirror row (j-col), c16 over i
      uint4 o = *reinterpret_cast<const uint4*>(sP + row * 136 + c16 * 8);
      *reinterpret_cast<uint4*>(Pg + (long)(j0 + row) * SEQ + i0 + c16 * 8) = o;
    }
  }
}

// ---------------- gemm2 (2-phase prefetch, BK=64 — r5 proven, 44.2us): out = (P.x)/l ------
// grid 512 = 8 batches x 16 i x 4 d ; 256 threads ; d-FAST ordering.
// B staging reads the BLOCKED-16 xt layout: j = kc*64 + sub*8 lives in chunk
// kc*4 + (sub>>1), row (n0+row), offset (sub&1)*8. Same bytes -> same sB slots.
__global__ __launch_bounds__(256, 2) void gemm2_kernel(const unsigned short* __restrict__ P,
                                                       const unsigned short* __restrict__ xt,
                                                       const float* __restrict__ lw,
                                                       float* __restrict__ out) {
  const int b  = blockIdx.x & 7;
  const int t  = blockIdx.x >> 3;
  const int i0 = (t >> 2) * 128;       // d-fast: i0 slow
  const int n0 = (t & 3) * 128;        // d-fast: n0 fast
  const int tid  = threadIdx.x;
  const int w    = tid >> 6;
  const int lane = tid & 63;
  const int ln   = lane & 31;
  const int half = lane >> 5;

  __shared__ __align__(16) unsigned short smem[32768];   // 64 KB dbuf
  __shared__ float sl[128];

  const unsigned short* Ag = P  + (long)b * SEQ * SEQ + (long)i0 * SEQ;
  const unsigned short* Bg = xt + (size_t)b * DIM * SEQ;   // blocked chunks base

  if (tid < 128) sl[tid] = lw[b * SEQ + i0 + tid];

  floatx16 acc[2][2];
#pragma unroll
  for (int mt = 0; mt < 2; ++mt)
#pragma unroll
    for (int nt = 0; nt < 2; ++nt)
#pragma unroll
      for (int i = 0; i < 16; ++i) acc[mt][nt][i] = 0.f;

  const int r0 = (w >> 1) * 64;
  const int c0 = (w & 1) * 64;

  // ---- prologue: stage kc=0 ----
  {
    unsigned short* bA = smem;
    unsigned short* bB = smem + 8192;
#pragma unroll
    for (int k = 0; k < 4; ++k) {
      int u = tid + k * 256;
      int row = u >> 3, c = u & 7;
      int sub = c ^ ((row ^ (row >> 3)) & 7);
      gld_lds16(Ag + (long)row * SEQ + sub * 8, bA + u * 8);
      gld_lds16(Bg + ((size_t)(sub >> 1) * 512 + (n0 + row)) * 16 + (sub & 1) * 8, bB + u * 8);
    }
  }
  wait_vm0_barrier();

  for (int kc = 0; kc < 32; ++kc) {
    const int cur = kc & 1;
    if (kc < 31) {
      unsigned short* bA = smem + (cur ^ 1) * 16384;
      unsigned short* bB = bA + 8192;
      const int kn = kc + 1;
#pragma unroll
      for (int k = 0; k < 4; ++k) {
        int u = tid + k * 256;
        int row = u >> 3, c = u & 7;
        int sub = c ^ ((row ^ (row >> 3)) & 7);
        gld_lds16(Ag + (long)row * SEQ + kn * 64 + sub * 8, bA + u * 8);
        gld_lds16(Bg + ((size_t)(kn * 4 + (sub >> 1)) * 512 + (n0 + row)) * 16 + (sub & 1) * 8,
                  bB + u * 8);
      }
      __builtin_amdgcn_sched_barrier(0);
    }
    unsigned short* cAb = smem + cur * 16384;
    unsigned short* cBb = cAb + 8192;
#pragma unroll
    for (int kk = 0; kk < 4; ++kk) {
      const int cc = kk * 2 + half;
      short8 af[2], bfr[2];
#pragma unroll
      for (int mt = 0; mt < 2; ++mt) {
        int r = r0 + mt * 32 + ln;
        af[mt] = ld_frag8(cAb + r * 64 + ((cc ^ ((r ^ (r >> 3)) & 7)) * 8));
      }
#pragma unroll
      for (int nt = 0; nt < 2; ++nt) {
        int r = c0 + nt * 32 + ln;
        bfr[nt] = ld_frag8(cBb + r * 64 + ((cc ^ ((r ^ (r >> 3)) & 7)) * 8));
      }
#pragma unroll
      for (int mt = 0; mt < 2; ++mt)
#pragma unroll
        for (int nt = 0; nt < 2; ++nt)
          acc[mt][nt] = __builtin_amdgcn_mfma_f32_32x32x16_bf16(af[mt], bfr[nt], acc[mt][nt], 0, 0, 0);
    }
    wait_vm0_barrier();
  }

  // epilogue: divide by l, coalesced fp32 stores
  float* outb = out + (long)b * SEQ * DIM;
#pragma unroll
  for (int mt = 0; mt < 2; ++mt)
#pragma unroll
    for (int r = 0; r < 16; ++r) {
      const int row = r0 + mt * 32 + (r & 3) + 8 * (r >> 2) + 4 * half;
      const float inv = 1.0f / sl[row];
#pragma unroll
      for (int nt = 0; nt < 2; ++nt) {
        const int col = c0 + nt * 32 + ln;
        outb[(long)(i0 + row) * DIM + n0 + col] = acc[mt][nt][r] * inv;
      }
    }
}

extern "C" void kernel_launch(void* const* d_in, const int* in_sizes, int n_in,
                              void* d_out, int out_size, void* d_ws, size_t ws_size,
                              hipStream_t stream) {
  const float* x = (const float*)d_in[0];
  float* outp = (float*)d_out;

  unsigned short* xn = (unsigned short*)d_ws;                        // 16.78 MB
  unsigned short* xt = xn + (size_t)BATCH * SEQ * DIM;               // 16.78 MB (blocked-16)
  unsigned short* Pw = xt + (size_t)BATCH * SEQ * DIM;               // 67.1 MB
  float*          lw = (float*)(Pw + (size_t)BATCH * SEQ * SEQ);     // 64 KB

  hipMemsetAsync(lw, 0, (size_t)BATCH * SEQ * sizeof(float), stream);
  prep_kernel <<<BATCH * (SEQ / 16),  256, 0, stream>>>(x, xn, xt);
  gemm1_kernel<<<BATCH * 136,         256, 0, stream>>>(xn, Pw, lw);
  gemm2_kernel<<<BATCH * 16 * 4,      256, 0, stream>>>(Pw, xt, lw, outp);
}